// Round 6
// baseline (206.224 us; speedup 1.0000x reference)
//
#include <hip/hip_runtime.h>
#include <hip/hip_fp16.h>

#define N_ITEMS 100000
#define HID 128
#define NNZ_T 1600000
#define PREPW_BLOCKS 64            // 16384 / 256 W-convert blocks
#define RP_BLOCKS 391              // ceil(100001/256) binary-search blocks
#define GEMM_BLOCKS 1563           // ceil(100000/64), 1 tile per block
#define SPMM_BLOCKS 25000          // 1 row per wave, 4 waves/block (frozen r5)

typedef unsigned short ushort_t;
typedef unsigned int uint_t;
typedef short bf16x8 __attribute__((ext_vector_type(8)));
typedef float f32x4 __attribute__((ext_vector_type(4)));

static __device__ __forceinline__ ushort_t f32_to_bf16(float f) {
    uint_t u = __float_as_uint(f);
    uint_t r = (u + 0x7FFFu + ((u >> 16) & 1u)) >> 16;   // RNE
    return (ushort_t)r;
}

// === K0: W fp32->bf16 (64 blocks) + row_ptr binary searches (391 blocks) ===
__global__ void prep(const float* __restrict__ W, const int* __restrict__ rows,
                     ushort_t* __restrict__ Wb, int* __restrict__ row_ptr) {
    if (blockIdx.x < PREPW_BLOCKS) {
        int i = blockIdx.x * 256 + threadIdx.x;
        Wb[i] = f32_to_bf16(W[i]);
        return;
    }
    int r = (blockIdx.x - PREPW_BLOCKS) * 256 + threadIdx.x;
    if (r > N_ITEMS) return;
    int lo = 0, hi = NNZ_T;
    while (lo < hi) {                       // lower_bound(rows, r), rows sorted
        int mid = (lo + hi) >> 1;
        if (rows[mid] < r) lo = mid + 1; else hi = mid;
    }
    row_ptr[r] = lo;
}

// === K1: S = fp16(X @ W^T + b), STAGE-FREE: no LDS, no __syncthreads.
// Wb (32 KB bf16) is read directly through L1 — per wf-load the wave touches
// 16 rows x 64B = 16 full lines, every byte consumed. 1 tile (64 rows) per
// block; diagnostic round: if this kernel is the hidden ~60us it now shows in
// top-5 with counters; if staging/sync was the cost it drops to ~10-15us.
__global__ __launch_bounds__(256) void gemm_mfma(
    const float* __restrict__ X, const ushort_t* __restrict__ Wb,
    const float* __restrict__ bias, ushort_t* __restrict__ S) {
    const int lane = threadIdx.x & 63;
    const int wave = threadIdx.x >> 6;
    const int m = lane & 15;
    const int q = lane >> 4;
    const int row0 = blockIdx.x * 64 + wave * 16;

    int arow = row0 + m;
    if (arow >= N_ITEMS) arow = N_ITEMS - 1;   // clamp (stores guarded)

    f32x4 acc[8] = {};
#pragma unroll
    for (int kb = 0; kb < 4; ++kb) {
        const int k0 = kb * 32 + q * 8;
        float4 a0 = *(const float4*)&X[(size_t)arow * HID + k0];
        float4 a1 = *(const float4*)&X[(size_t)arow * HID + k0 + 4];
        bf16x8 xf;
        xf[0] = (short)f32_to_bf16(a0.x); xf[1] = (short)f32_to_bf16(a0.y);
        xf[2] = (short)f32_to_bf16(a0.z); xf[3] = (short)f32_to_bf16(a0.w);
        xf[4] = (short)f32_to_bf16(a1.x); xf[5] = (short)f32_to_bf16(a1.y);
        xf[6] = (short)f32_to_bf16(a1.z); xf[7] = (short)f32_to_bf16(a1.w);
#pragma unroll
        for (int nt = 0; nt < 8; ++nt) {
            const bf16x8 wf = *(const bf16x8*)&Wb[(size_t)(nt * 16 + m) * HID + k0];
            acc[nt] = __builtin_amdgcn_mfma_f32_16x16x32_bf16(wf, xf, acc[nt], 0, 0, 0);
        }
    }

    const int srow = row0 + m;
    const bool ok = srow < N_ITEMS;
#pragma unroll
    for (int nt = 0; nt < 8; ++nt) {
        const int c0 = nt * 16 + q * 4;     // 4 consecutive out cols
        float4 bv = *(const float4*)&bias[c0];
        ushort_t h0 = __half_as_ushort(__float2half(acc[nt][0] + bv.x));
        ushort_t h1 = __half_as_ushort(__float2half(acc[nt][1] + bv.y));
        ushort_t h2 = __half_as_ushort(__float2half(acc[nt][2] + bv.z));
        ushort_t h3 = __half_as_ushort(__float2half(acc[nt][3] + bv.w));
        uint2 pk;
        pk.x = (uint_t)h0 | ((uint_t)h1 << 16);
        pk.y = (uint_t)h2 | ((uint_t)h3 << 16);
        if (ok) *(uint2*)&S[(size_t)srow * HID + c0] = pk;
    }
}

// === K2: FROZEN round-5 spmm (measured 60.8us, ~3.9 TB/s local roofline) ===
__global__ __launch_bounds__(256) void spmm_csr(
    const int* __restrict__ cols, const float* __restrict__ vals,
    const int* __restrict__ row_ptr, const ushort_t* __restrict__ S,
    float* __restrict__ out) {
    const int lane = threadIdx.x & 63;
    const int r = blockIdx.x * 4 + (threadIdx.x >> 6);    // one row per wave
    if (r >= N_ITEMS) return;

    const int g = lane >> 4;                // edge slot within a quad (0..3)
    const int l = lane & 15;                // column octet: cols 8*l .. 8*l+7

    int pa = row_ptr[r];
    const int pE = row_ptr[r + 1];

    __half2 acc[4];
#pragma unroll
    for (int j = 0; j < 4; ++j) acc[j] = __float2half2_rn(0.f);

    while (pa < pE) {
        // lanes 0-15 load 16 contiguous (col,val); other groups duplicate (1 line)
        const int idx  = pa + l;
        const int cidx = min(idx, pE - 1);            // pE > pa >= 0 here
        const int c_l  = cols[cidx];
        const float v_l = (idx < pE) ? vals[cidx] : 0.f;

        uint4 u[4];
        float vv[4];
#pragma unroll
        for (int t = 0; t < 4; ++t) {                 // 4 quad-gathers in flight
            const int s = 4 * t + g;                  // slot index 0..15
            const int ct = __shfl(c_l, s, 64);
            vv[t] = __shfl(v_l, s, 64);
            u[t] = *(const uint4*)&S[(size_t)ct * HID + 8 * l];
        }
#pragma unroll
        for (int t = 0; t < 4; ++t) {
            const __half2 w = __float2half2_rn(vv[t]);
            acc[0] = __hfma2(w, *(const __half2*)&u[t].x, acc[0]);
            acc[1] = __hfma2(w, *(const __half2*)&u[t].y, acc[1]);
            acc[2] = __hfma2(w, *(const __half2*)&u[t].z, acc[2]);
            acc[3] = __hfma2(w, *(const __half2*)&u[t].w, acc[3]);
        }
        pa += 16;
    }

    // unpack to f32; reduce over the 4 edge-groups (lanes l, l+16, l+32, l+48)
    float f[8];
#pragma unroll
    for (int j = 0; j < 4; ++j) {
        f[2 * j] = __low2float(acc[j]);  f[2 * j + 1] = __high2float(acc[j]);
    }
#pragma unroll
    for (int e = 0; e < 8; ++e) {
        f[e] += __shfl_xor(f[e], 16, 64);
        f[e] += __shfl_xor(f[e], 32, 64);
    }
    if (g == 0) {                           // lanes 0-15 store the 512B row
        float* p = &out[(size_t)r * HID + 8 * l];
        *(float4*)p       = make_float4(f[0], f[1], f[2], f[3]);
        *(float4*)(p + 4) = make_float4(f[4], f[5], f[6], f[7]);
    }
}

extern "C" void kernel_launch(void* const* d_in, const int* in_sizes, int n_in,
                              void* d_out, int out_size, void* d_ws, size_t ws_size,
                              hipStream_t stream) {
    const float* X    = (const float*)d_in[0];
    const int*   rows = (const int*)  d_in[1];
    const int*   cols = (const int*)  d_in[2];
    const float* vals = (const float*)d_in[3];
    const float* W    = (const float*)d_in[4];
    const float* bias = (const float*)d_in[5];
    float* out = (float*)d_out;

    ushort_t* Wb      = (ushort_t*)d_ws;                    // 32 KB (bf16)
    ushort_t* S       = Wb + HID * HID;                     // 25.6 MB (fp16)
    int*      row_ptr = (int*)(S + (size_t)N_ITEMS * HID);  // 400 KB

    prep<<<PREPW_BLOCKS + RP_BLOCKS, 256, 0, stream>>>(W, rows, Wb, row_ptr);
    gemm_mfma<<<GEMM_BLOCKS, 256, 0, stream>>>(X, Wb, bias, S);
    spmm_csr<<<SPMM_BLOCKS, 256, 0, stream>>>(cols, vals, row_ptr, S, out);
}